// Round 1
// baseline (3633.046 us; speedup 1.0000x reference)
//
#include <hip/hip_runtime.h>

#define N_NODES 50000
#define N_EDGES 600000
#define DIM 128
#define N_GRAPHS 512
#define N_LAYERS 3
#define OUT_STRIDE (N_LAYERS * DIM)
#define BN_EPS 1e-5f

// ---------------- copy h -> agg (GIN self term, eps=0) ----------------
__global__ __launch_bounds__(256) void copy_kernel(const float* __restrict__ src,
                                                   float* __restrict__ dst, int n4) {
    int t = blockIdx.x * 256 + threadIdx.x;
    if (t < n4) ((float4*)dst)[t] = ((const float4*)src)[t];
}

// ---------------- edge scatter: agg[dst] += h[src] ----------------
// thread = (edge, 4-feature chunk); float4 gather + 4 scalar atomics
__global__ __launch_bounds__(256) void scatter_kernel(const float* __restrict__ hin,
                                                      const int* __restrict__ src,
                                                      const int* __restrict__ dst,
                                                      float* __restrict__ agg) {
    int t = blockIdx.x * 256 + threadIdx.x;
    int e = t >> 5;
    if (e >= N_EDGES) return;
    int f = (t & 31) * 4;
    int s = src[e], d = dst[e];
    float4 v = *(const float4*)(hin + (size_t)s * DIM + f);
    float* ap = agg + (size_t)d * DIM + f;
    atomicAdd(ap + 0, v.x);
    atomicAdd(ap + 1, v.y);
    atomicAdd(ap + 2, v.z);
    atomicAdd(ap + 3, v.w);
}

// ---------------- fp32 GEMM: out = relu?(in @ W + b), in [M,128], W [128,128] ----------------
// block = 256 threads, 32-row tile in LDS; thread: col c = tid&127, 16 rows.
// LDS reads are wave-uniform (broadcast, conflict-free) ds_read_b128.
template <int RELU>
__global__ __launch_bounds__(256) void gemm_kernel(const float* __restrict__ in,
                                                   const float* __restrict__ W,
                                                   const float* __restrict__ bias,
                                                   float* __restrict__ out) {
    __shared__ float tin[32 * DIM];
    int base = blockIdx.x * 32;
    for (int idx = threadIdx.x; idx < 32 * DIM; idx += 256) {
        int r = base + (idx >> 7);
        tin[idx] = (r < N_NODES) ? in[(size_t)r * DIM + (idx & 127)] : 0.f;
    }
    __syncthreads();
    int c = threadIdx.x & 127;
    int rr = (threadIdx.x >> 7) * 16;  // 0 or 16
    float acc[16];
#pragma unroll
    for (int i = 0; i < 16; ++i) acc[i] = 0.f;
    for (int k4 = 0; k4 < DIM / 4; ++k4) {
        float w0 = W[(k4 * 4 + 0) * DIM + c];
        float w1 = W[(k4 * 4 + 1) * DIM + c];
        float w2 = W[(k4 * 4 + 2) * DIM + c];
        float w3 = W[(k4 * 4 + 3) * DIM + c];
#pragma unroll
        for (int i = 0; i < 16; ++i) {
            float4 t = *(const float4*)&tin[(rr + i) * DIM + k4 * 4];
            acc[i] = fmaf(t.x, w0, acc[i]);
            acc[i] = fmaf(t.y, w1, acc[i]);
            acc[i] = fmaf(t.z, w2, acc[i]);
            acc[i] = fmaf(t.w, w3, acc[i]);
        }
    }
    float bv = bias[c];
#pragma unroll
    for (int i = 0; i < 16; ++i) {
        int r = base + rr + i;
        if (r < N_NODES) {
            float v = acc[i] + bv;
            if (RELU) v = fmaxf(v, 0.f);
            out[(size_t)r * DIM + c] = v;
        }
    }
}

// ---------------- BN stats: per-feature sum & sumsq ----------------
__global__ __launch_bounds__(256) void bn_stats_kernel(const float* __restrict__ h2,
                                                       float* __restrict__ stats) {
    int c = threadIdx.x & 127;
    int rs = threadIdx.x >> 7;  // 0/1
    float sum = 0.f, sq = 0.f;
    for (int row = blockIdx.x * 2 + rs; row < N_NODES; row += gridDim.x * 2) {
        float v = h2[(size_t)row * DIM + c];
        sum += v;
        sq += v * v;
    }
    __shared__ float red[256];
    red[threadIdx.x] = sum;
    __syncthreads();
    if (rs == 0) atomicAdd(&stats[c], sum + red[threadIdx.x + 128]);
    __syncthreads();
    red[threadIdx.x] = sq;
    __syncthreads();
    if (rs == 0) atomicAdd(&stats[128 + c], sq + red[threadIdx.x + 128]);
}

// ---------------- BN apply + global_add_pool ----------------
__global__ __launch_bounds__(256) void bn_apply_pool_kernel(const float* __restrict__ h2,
                                                            const float* __restrict__ stats,
                                                            const float* __restrict__ gamma,
                                                            const float* __restrict__ beta,
                                                            const int* __restrict__ batch,
                                                            float* __restrict__ hout,
                                                            float* __restrict__ out, int layer) {
    int c = threadIdx.x & 127;
    int rs = threadIdx.x >> 7;
    const float invn = 1.0f / (float)N_NODES;
    float mean = stats[c] * invn;
    float var = stats[128 + c] * invn - mean * mean;
    float inv = rsqrtf(var + BN_EPS);
    float g = gamma[c], b = beta[c];
    for (int row = blockIdx.x * 2 + rs; row < N_NODES; row += gridDim.x * 2) {
        float v = h2[(size_t)row * DIM + c];
        float y = (v - mean) * inv * g + b;
        hout[(size_t)row * DIM + c] = y;
        atomicAdd(&out[(size_t)batch[row] * OUT_STRIDE + layer * DIM + c], y);
    }
}

extern "C" void kernel_launch(void* const* d_in, const int* in_sizes, int n_in,
                              void* d_out, int out_size, void* d_ws, size_t ws_size,
                              hipStream_t stream) {
    const float* x = (const float*)d_in[0];
    const int* ei = (const int*)d_in[1];
    const int* srcp = ei;
    const int* dstp = ei + N_EDGES;
    const int* batch = (const int*)d_in[2];
    const float* W1s = (const float*)d_in[3];
    const float* b1s = (const float*)d_in[4];
    const float* W2s = (const float*)d_in[5];
    const float* b2s = (const float*)d_in[6];
    const float* gammas = (const float*)d_in[7];
    const float* betas = (const float*)d_in[8];
    float* out = (float*)d_out;

    float* ws = (float*)d_ws;
    float* h = ws;                       // 6.4M floats
    float* agg = ws + (size_t)N_NODES * DIM;       // 6.4M floats (also holds h2)
    float* h1 = ws + 2 * (size_t)N_NODES * DIM;    // 6.4M floats
    float* stats = ws + 3 * (size_t)N_NODES * DIM; // 256 floats

    hipMemsetAsync(out, 0, (size_t)N_GRAPHS * OUT_STRIDE * sizeof(float), stream);

    const int n4 = N_NODES * DIM / 4;
    const float* hin = x;
    for (int layer = 0; layer < N_LAYERS; ++layer) {
        copy_kernel<<<(n4 + 255) / 256, 256, 0, stream>>>(hin, agg, n4);
        scatter_kernel<<<(N_EDGES * 32 + 255) / 256, 256, 0, stream>>>(hin, srcp, dstp, agg);
        gemm_kernel<1><<<(N_NODES + 31) / 32, 256, 0, stream>>>(
            agg, W1s + (size_t)layer * DIM * DIM, b1s + layer * DIM, h1);
        gemm_kernel<1><<<(N_NODES + 31) / 32, 256, 0, stream>>>(
            h1, W2s + (size_t)layer * DIM * DIM, b2s + layer * DIM, agg);  // h2 -> agg
        hipMemsetAsync(stats, 0, 256 * sizeof(float), stream);
        bn_stats_kernel<<<512, 256, 0, stream>>>(agg, stats);
        bn_apply_pool_kernel<<<512, 256, 0, stream>>>(agg, stats, gammas + layer * DIM,
                                                      betas + layer * DIM, batch, h, out, layer);
        hin = h;
    }
}

// Round 2
// 923.180 us; speedup vs baseline: 3.9354x; 3.9354x over previous
//
#include <hip/hip_runtime.h>

#define N_NODES 50000
#define N_EDGES 600000
#define DIM 128
#define N_GRAPHS 512
#define N_LAYERS 3
#define OUT_STRIDE (N_LAYERS * DIM)
#define BN_EPS 1e-5f

// ---------------- CSR build: degree count ----------------
__global__ __launch_bounds__(256) void degree_kernel(const int* __restrict__ dst,
                                                     int* __restrict__ deg) {
    int e = blockIdx.x * 256 + threadIdx.x;
    if (e < N_EDGES) atomicAdd(&deg[dst[e]], 1);
}

// ---------------- CSR build: exclusive scan (single block, chunked) ----------------
__global__ __launch_bounds__(1024) void scan_kernel(const int* __restrict__ deg,
                                                    int* __restrict__ ptr,
                                                    int* __restrict__ cursor) {
    __shared__ int buf[1024];
    __shared__ int carry;
    if (threadIdx.x == 0) carry = 0;
    __syncthreads();
    for (int base = 0; base < N_NODES; base += 1024) {
        int i = base + (int)threadIdx.x;
        int v = (i < N_NODES) ? deg[i] : 0;
        buf[threadIdx.x] = v;
        __syncthreads();
        for (int off = 1; off < 1024; off <<= 1) {
            int t = (threadIdx.x >= off) ? buf[threadIdx.x - off] : 0;
            __syncthreads();
            buf[threadIdx.x] += t;
            __syncthreads();
        }
        int excl = carry + buf[threadIdx.x] - v;
        if (i < N_NODES) { ptr[i] = excl; cursor[i] = excl; }
        __syncthreads();
        if (threadIdx.x == 1023) carry += buf[1023];
        __syncthreads();
    }
    if (threadIdx.x == 0) ptr[N_NODES] = N_EDGES;
}

// ---------------- CSR build: fill edge lists ----------------
__global__ __launch_bounds__(256) void fill_kernel(const int* __restrict__ src,
                                                   const int* __restrict__ dst,
                                                   int* __restrict__ cursor,
                                                   int* __restrict__ esrc) {
    int e = blockIdx.x * 256 + threadIdx.x;
    if (e < N_EDGES) {
        int slot = atomicAdd(&cursor[dst[e]], 1);
        esrc[slot] = src[e];
    }
}

// ---------------- gather: agg[n] = h[n] + sum_{j in N(n)} h[j] ----------------
// one wave per node; lane l holds float2 at feature offset 2l; coalesced 512B per neighbor
__global__ __launch_bounds__(256) void gather_kernel(const float* __restrict__ hin,
                                                     const int* __restrict__ ptr,
                                                     const int* __restrict__ esrc,
                                                     float* __restrict__ agg) {
    int node = (blockIdx.x * 256 + threadIdx.x) >> 6;
    int lane = threadIdx.x & 63;
    if (node >= N_NODES) return;
    const float2* h2p = (const float2*)hin;
    float2 acc = h2p[(size_t)node * 64 + lane];  // self term (eps=0)
    int b = ptr[node], e = ptr[node + 1];
    for (int j = b; j < e; ++j) {
        int s = esrc[j];
        float2 v = h2p[(size_t)s * 64 + lane];
        acc.x += v.x;
        acc.y += v.y;
    }
    ((float2*)agg)[(size_t)node * 64 + lane] = acc;
}

// ---------------- fp32 GEMM: out = relu?(in @ W + b), in [M,128], W [128,128] ----------------
template <int RELU>
__global__ __launch_bounds__(256) void gemm_kernel(const float* __restrict__ in,
                                                   const float* __restrict__ W,
                                                   const float* __restrict__ bias,
                                                   float* __restrict__ out) {
    __shared__ float tin[32 * DIM];
    int base = blockIdx.x * 32;
    for (int idx = threadIdx.x; idx < 32 * DIM; idx += 256) {
        int r = base + (idx >> 7);
        tin[idx] = (r < N_NODES) ? in[(size_t)r * DIM + (idx & 127)] : 0.f;
    }
    __syncthreads();
    int c = threadIdx.x & 127;
    int rr = (threadIdx.x >> 7) * 16;  // 0 or 16
    float acc[16];
#pragma unroll
    for (int i = 0; i < 16; ++i) acc[i] = 0.f;
    for (int k4 = 0; k4 < DIM / 4; ++k4) {
        float w0 = W[(k4 * 4 + 0) * DIM + c];
        float w1 = W[(k4 * 4 + 1) * DIM + c];
        float w2 = W[(k4 * 4 + 2) * DIM + c];
        float w3 = W[(k4 * 4 + 3) * DIM + c];
#pragma unroll
        for (int i = 0; i < 16; ++i) {
            float4 t = *(const float4*)&tin[(rr + i) * DIM + k4 * 4];
            acc[i] = fmaf(t.x, w0, acc[i]);
            acc[i] = fmaf(t.y, w1, acc[i]);
            acc[i] = fmaf(t.z, w2, acc[i]);
            acc[i] = fmaf(t.w, w3, acc[i]);
        }
    }
    float bv = bias[c];
#pragma unroll
    for (int i = 0; i < 16; ++i) {
        int r = base + rr + i;
        if (r < N_NODES) {
            float v = acc[i] + bv;
            if (RELU) v = fmaxf(v, 0.f);
            out[(size_t)r * DIM + c] = v;
        }
    }
}

// ---------------- BN stats: per-feature sum & sumsq ----------------
__global__ __launch_bounds__(256) void bn_stats_kernel(const float* __restrict__ h2,
                                                       float* __restrict__ stats) {
    int c = threadIdx.x & 127;
    int rs = threadIdx.x >> 7;  // 0/1
    float sum = 0.f, sq = 0.f;
    for (int row = blockIdx.x * 2 + rs; row < N_NODES; row += gridDim.x * 2) {
        float v = h2[(size_t)row * DIM + c];
        sum += v;
        sq += v * v;
    }
    __shared__ float red[256];
    red[threadIdx.x] = sum;
    __syncthreads();
    if (rs == 0) atomicAdd(&stats[c], sum + red[threadIdx.x + 128]);
    __syncthreads();
    red[threadIdx.x] = sq;
    __syncthreads();
    if (rs == 0) atomicAdd(&stats[128 + c], sq + red[threadIdx.x + 128]);
}

// ---------------- BN apply + global_add_pool ----------------
__global__ __launch_bounds__(256) void bn_apply_pool_kernel(const float* __restrict__ h2,
                                                            const float* __restrict__ stats,
                                                            const float* __restrict__ gamma,
                                                            const float* __restrict__ beta,
                                                            const int* __restrict__ batch,
                                                            float* __restrict__ hout,
                                                            float* __restrict__ out, int layer) {
    int c = threadIdx.x & 127;
    int rs = threadIdx.x >> 7;
    const float invn = 1.0f / (float)N_NODES;
    float mean = stats[c] * invn;
    float var = stats[128 + c] * invn - mean * mean;
    float inv = rsqrtf(var + BN_EPS);
    float g = gamma[c], b = beta[c];
    for (int row = blockIdx.x * 2 + rs; row < N_NODES; row += gridDim.x * 2) {
        float v = h2[(size_t)row * DIM + c];
        float y = (v - mean) * inv * g + b;
        hout[(size_t)row * DIM + c] = y;
        atomicAdd(&out[(size_t)batch[row] * OUT_STRIDE + layer * DIM + c], y);
    }
}

extern "C" void kernel_launch(void* const* d_in, const int* in_sizes, int n_in,
                              void* d_out, int out_size, void* d_ws, size_t ws_size,
                              hipStream_t stream) {
    const float* x = (const float*)d_in[0];
    const int* ei = (const int*)d_in[1];
    const int* srcp = ei;
    const int* dstp = ei + N_EDGES;
    const int* batch = (const int*)d_in[2];
    const float* W1s = (const float*)d_in[3];
    const float* b1s = (const float*)d_in[4];
    const float* W2s = (const float*)d_in[5];
    const float* b2s = (const float*)d_in[6];
    const float* gammas = (const float*)d_in[7];
    const float* betas = (const float*)d_in[8];
    float* out = (float*)d_out;

    float* ws = (float*)d_ws;
    float* h = ws;                                  // 6.4M floats
    float* agg = ws + (size_t)N_NODES * DIM;        // 6.4M floats (also h2)
    float* h1 = ws + 2 * (size_t)N_NODES * DIM;     // 6.4M floats
    float* stats = ws + 3 * (size_t)N_NODES * DIM;  // 256 floats
    int* ibase = (int*)(stats + 256);
    int* deg = ibase;                 // 50000
    int* ptr = ibase + N_NODES;       // 50001
    int* cursor = ibase + 2 * N_NODES + 1;  // 50000
    int* esrc = ibase + 3 * N_NODES + 1;    // 600000

    hipMemsetAsync(out, 0, (size_t)N_GRAPHS * OUT_STRIDE * sizeof(float), stream);
    hipMemsetAsync(deg, 0, N_NODES * sizeof(int), stream);

    // Build CSR (indexed by dst) once; reused by all 3 layers.
    degree_kernel<<<(N_EDGES + 255) / 256, 256, 0, stream>>>(dstp, deg);
    scan_kernel<<<1, 1024, 0, stream>>>(deg, ptr, cursor);
    fill_kernel<<<(N_EDGES + 255) / 256, 256, 0, stream>>>(srcp, dstp, cursor, esrc);

    const float* hin = x;
    for (int layer = 0; layer < N_LAYERS; ++layer) {
        gather_kernel<<<(N_NODES * 64 + 255) / 256, 256, 0, stream>>>(hin, ptr, esrc, agg);
        gemm_kernel<1><<<(N_NODES + 31) / 32, 256, 0, stream>>>(
            agg, W1s + (size_t)layer * DIM * DIM, b1s + layer * DIM, h1);
        gemm_kernel<1><<<(N_NODES + 31) / 32, 256, 0, stream>>>(
            h1, W2s + (size_t)layer * DIM * DIM, b2s + layer * DIM, agg);  // h2 -> agg
        hipMemsetAsync(stats, 0, 256 * sizeof(float), stream);
        bn_stats_kernel<<<512, 256, 0, stream>>>(agg, stats);
        bn_apply_pool_kernel<<<512, 256, 0, stream>>>(agg, stats, gammas + layer * DIM,
                                                      betas + layer * DIM, batch, h, out, layer);
        hin = h;
    }
}

// Round 4
// 643.756 us; speedup vs baseline: 5.6435x; 1.4341x over previous
//
#include <hip/hip_runtime.h>

#define N_NODES 50000
#define N_EDGES 600000
#define DIM 128
#define N_GRAPHS 512
#define N_LAYERS 3
#define OUT_STRIDE (N_LAYERS * DIM)
#define BN_EPS 1e-5f
#define N_CHUNKS 49  // ceil(50000/1024)

typedef __attribute__((ext_vector_type(8))) short short8;
typedef __attribute__((ext_vector_type(4))) float floatx4;

__device__ inline short f2bf(float f) {
    union { float f; unsigned u; } x{f};
    unsigned r = x.u + 0x7fffu + ((x.u >> 16) & 1u);
    return (short)(r >> 16);
}
__device__ inline float bf2f(short h) {
    union { unsigned u; float f; } x;
    x.u = ((unsigned)(unsigned short)h) << 16;
    return x.f;
}

// ---------------- CSR build ----------------
__global__ __launch_bounds__(256) void degree_kernel(const int* __restrict__ dst,
                                                     int* __restrict__ deg) {
    int e = blockIdx.x * 256 + threadIdx.x;
    if (e < N_EDGES) atomicAdd(&deg[dst[e]], 1);
}

__global__ __launch_bounds__(1024) void scan1_kernel(const int* __restrict__ deg,
                                                     int* __restrict__ ptr,
                                                     int* __restrict__ partials) {
    __shared__ int buf[1024];
    int i = blockIdx.x * 1024 + threadIdx.x;
    int v = (i < N_NODES) ? deg[i] : 0;
    buf[threadIdx.x] = v;
    __syncthreads();
    for (int off = 1; off < 1024; off <<= 1) {
        int t = (threadIdx.x >= (unsigned)off) ? buf[threadIdx.x - off] : 0;
        __syncthreads();
        buf[threadIdx.x] += t;
        __syncthreads();
    }
    if (i < N_NODES) ptr[i] = buf[threadIdx.x] - v;  // chunk-local exclusive
    if (threadIdx.x == 1023) partials[blockIdx.x] = buf[1023];
}

__global__ __launch_bounds__(64) void scan2_kernel(int* __restrict__ partials) {
    if (threadIdx.x == 0) {
        int run = 0;
        for (int i = 0; i < N_CHUNKS; ++i) { int t = partials[i]; partials[i] = run; run += t; }
    }
}

__global__ __launch_bounds__(256) void scan3_kernel(const int* __restrict__ partials,
                                                    int* __restrict__ ptr,
                                                    int* __restrict__ cursor) {
    int i = blockIdx.x * 256 + threadIdx.x;
    if (i < N_NODES) {
        int p = ptr[i] + partials[i >> 10];
        ptr[i] = p;
        cursor[i] = p;
    }
    if (i == N_NODES) ptr[N_NODES] = N_EDGES;
}

__global__ __launch_bounds__(256) void fill_kernel(const int* __restrict__ src,
                                                   const int* __restrict__ dst,
                                                   int* __restrict__ cursor,
                                                   int* __restrict__ esrc) {
    int e = blockIdx.x * 256 + threadIdx.x;
    if (e < N_EDGES) {
        int slot = atomicAdd(&cursor[dst[e]], 1);
        esrc[slot] = src[e];
    }
}

// ---------------- weight convert: W[k][n] -> Wt_hi/lo[mat][n][k] (split bf16) ----------------
__global__ __launch_bounds__(256) void wconv_kernel(const float* __restrict__ W1s,
                                                    const float* __restrict__ W2s,
                                                    short* __restrict__ Whi,
                                                    short* __restrict__ Wlo) {
    int idx = blockIdx.x * 256 + threadIdx.x;
    if (idx >= 6 * DIM * DIM) return;
    int mat = idx >> 14;
    int e = idx & 16383;
    int k = e >> 7, n = e & 127;
    const float* W = (mat < 3) ? (W1s + (size_t)mat * DIM * DIM)
                               : (W2s + (size_t)(mat - 3) * DIM * DIM);
    float w = W[e];
    short hi = f2bf(w);
    short lo = f2bf(w - bf2f(hi));
    size_t o = ((size_t)mat << 14) + n * DIM + k;
    Whi[o] = hi;
    Wlo[o] = lo;
}

// ---------------- gather: agg[n] = h[n] + sum_{j in N(n)} h[j] ----------------
__global__ __launch_bounds__(256) void gather_kernel(const float* __restrict__ hin,
                                                     const int* __restrict__ ptr,
                                                     const int* __restrict__ esrc,
                                                     float* __restrict__ agg) {
    int node = (blockIdx.x * 256 + threadIdx.x) >> 6;
    int lane = threadIdx.x & 63;
    if (node >= N_NODES) return;
    const float2* h2p = (const float2*)hin;
    float2 acc = h2p[(size_t)node * 64 + lane];  // self term (eps=0)
    int b = ptr[node], e = ptr[node + 1];
    for (int j = b; j < e; ++j) {
        int s = esrc[j];
        float2 v = h2p[(size_t)s * 64 + lane];
        acc.x += v.x;
        acc.y += v.y;
    }
    ((float2*)agg)[(size_t)node * 64 + lane] = acc;
}

// ---------------- split-bf16 MFMA GEMM: out = relu(in @ W + b), near-fp32 accuracy ----------
// 128x128 tile, 256 threads = 4 waves (each 64x64 = 4x4 MFMA tiles).
// A split hi/lo in LDS (XOR-swizzled, 64 KB); W hi/lo fragments read from global (L1/L2).
// 3-term compensation: Ahi*Whi + Alo*Whi + Ahi*Wlo. In-place safe (in==out).
__global__ __launch_bounds__(256) void mfma_gemm_kernel(const float* in,
                                                        const short* __restrict__ Whi,
                                                        const short* __restrict__ Wlo,
                                                        const float* __restrict__ bias,
                                                        float* out) {
    __shared__ short As_hi[128 * 128];
    __shared__ short As_lo[128 * 128];
    const int tid = threadIdx.x;
    const int base = blockIdx.x * 128;

    // stage A: 8 floats/thread/iter -> hi & lo 16B chunks, swizzled (chunk ^ (row&15))
    const float4* asrc = (const float4*)in;
#pragma unroll
    for (int it = 0; it < 8; ++it) {
        int c = tid + it * 256;  // 0..2047
        int r = c >> 4, ch = c & 15;
        int row = base + r;
        float4 v0 = make_float4(0.f, 0.f, 0.f, 0.f);
        float4 v1 = v0;
        if (row < N_NODES) {
            v0 = asrc[(size_t)row * 32 + ch * 2];
            v1 = asrc[(size_t)row * 32 + ch * 2 + 1];
        }
        float f[8] = {v0.x, v0.y, v0.z, v0.w, v1.x, v1.y, v1.z, v1.w};
        short8 hi, lo;
#pragma unroll
        for (int j = 0; j < 8; ++j) {
            short h = f2bf(f[j]);
            hi[j] = h;
            lo[j] = f2bf(f[j] - bf2f(h));
        }
        int pos = r * 128 + ((ch ^ (r & 15)) * 8);
        *(short8*)&As_hi[pos] = hi;
        *(short8*)&As_lo[pos] = lo;
    }
    __syncthreads();

    const int wave = tid >> 6;
    const int lane = tid & 63;
    const int wm = (wave & 1) * 64;
    const int wn = (wave >> 1) * 64;
    const int l15 = lane & 15;
    const int quad = lane >> 4;

    floatx4 acc[4][4];
#pragma unroll
    for (int mi = 0; mi < 4; ++mi)
#pragma unroll
        for (int ni = 0; ni < 4; ++ni) acc[mi][ni] = floatx4{0.f, 0.f, 0.f, 0.f};

#pragma unroll
    for (int ks = 0; ks < 4; ++ks) {
        int cb = ks * 4 + quad;
        short8 ahi[4], alo[4], bhi[4], blo[4];
#pragma unroll
        for (int mi = 0; mi < 4; ++mi) {
            int rl = wm + mi * 16 + l15;
            int p = rl * 128 + ((cb ^ l15) * 8);
            ahi[mi] = *(const short8*)&As_hi[p];
            alo[mi] = *(const short8*)&As_lo[p];
        }
#pragma unroll
        for (int ni = 0; ni < 4; ++ni) {
            size_t p = (size_t)(wn + ni * 16 + l15) * DIM + ks * 32 + quad * 8;
            bhi[ni] = *(const short8*)&Whi[p];
            blo[ni] = *(const short8*)&Wlo[p];
        }
#pragma unroll
        for (int mi = 0; mi < 4; ++mi)
#pragma unroll
            for (int ni = 0; ni < 4; ++ni) {
                acc[mi][ni] = __builtin_amdgcn_mfma_f32_16x16x32_bf16(ahi[mi], bhi[ni], acc[mi][ni], 0, 0, 0);
                acc[mi][ni] = __builtin_amdgcn_mfma_f32_16x16x32_bf16(alo[mi], bhi[ni], acc[mi][ni], 0, 0, 0);
                acc[mi][ni] = __builtin_amdgcn_mfma_f32_16x16x32_bf16(ahi[mi], blo[ni], acc[mi][ni], 0, 0, 0);
            }
    }

    // epilogue: C row = base+wm+mi*16+quad*4+reg, col = wn+ni*16+l15
    float bv[4];
#pragma unroll
    for (int ni = 0; ni < 4; ++ni) bv[ni] = bias[wn + ni * 16 + l15];
#pragma unroll
    for (int mi = 0; mi < 4; ++mi) {
#pragma unroll
        for (int reg = 0; reg < 4; ++reg) {
            int row = base + wm + mi * 16 + quad * 4 + reg;
            if (row < N_NODES) {
#pragma unroll
                for (int ni = 0; ni < 4; ++ni) {
                    int col = wn + ni * 16 + l15;
                    out[(size_t)row * DIM + col] = fmaxf(acc[mi][ni][reg] + bv[ni], 0.f);
                }
            }
        }
    }
}

// ---------------- BN stats: per-feature sum & sumsq ----------------
__global__ __launch_bounds__(256) void bn_stats_kernel(const float* __restrict__ h2,
                                                       float* __restrict__ stats) {
    int c = threadIdx.x & 127;
    int rs = threadIdx.x >> 7;  // 0/1
    float sum = 0.f, sq = 0.f;
    for (int row = blockIdx.x * 2 + rs; row < N_NODES; row += gridDim.x * 2) {
        float v = h2[(size_t)row * DIM + c];
        sum += v;
        sq += v * v;
    }
    __shared__ float red[256];
    red[threadIdx.x] = sum;
    __syncthreads();
    if (rs == 0) atomicAdd(&stats[c], sum + red[threadIdx.x + 128]);
    __syncthreads();
    red[threadIdx.x] = sq;
    __syncthreads();
    if (rs == 0) atomicAdd(&stats[128 + c], sq + red[threadIdx.x + 128]);
}

// ---------------- BN apply + segmented global_add_pool (batch sorted) ----------------
__global__ __launch_bounds__(128) void bn_apply_pool_kernel(const float* __restrict__ h2,
                                                            const float* __restrict__ stats,
                                                            const float* __restrict__ gamma,
                                                            const float* __restrict__ beta,
                                                            const int* __restrict__ batch,
                                                            float* __restrict__ hout,
                                                            float* __restrict__ out, int layer) {
    int c = threadIdx.x;  // 0..127
    int r0 = blockIdx.x * 128;
    int r1 = min(r0 + 128, N_NODES);
    const float invn = 1.0f / (float)N_NODES;
    float mean = stats[c] * invn;
    float var = stats[128 + c] * invn - mean * mean;
    float inv = rsqrtf(var + BN_EPS);
    float g = gamma[c] * inv;
    float off = beta[c] - mean * g;
    float acc = 0.f;
    int curb = batch[r0];
    for (int r = r0; r < r1; ++r) {
        int bb = batch[r];
        if (bb != curb) {
            atomicAdd(&out[(size_t)curb * OUT_STRIDE + layer * DIM + c], acc);
            acc = 0.f;
            curb = bb;
        }
        float v = h2[(size_t)r * DIM + c];
        float y = fmaf(v, g, off);
        hout[(size_t)r * DIM + c] = y;
        acc += y;
    }
    atomicAdd(&out[(size_t)curb * OUT_STRIDE + layer * DIM + c], acc);
}

extern "C" void kernel_launch(void* const* d_in, const int* in_sizes, int n_in,
                              void* d_out, int out_size, void* d_ws, size_t ws_size,
                              hipStream_t stream) {
    const float* x = (const float*)d_in[0];
    const int* ei = (const int*)d_in[1];
    const int* srcp = ei;
    const int* dstp = ei + N_EDGES;
    const int* batch = (const int*)d_in[2];
    const float* W1s = (const float*)d_in[3];
    const float* b1s = (const float*)d_in[4];
    const float* W2s = (const float*)d_in[5];
    const float* b2s = (const float*)d_in[6];
    const float* gammas = (const float*)d_in[7];
    const float* betas = (const float*)d_in[8];
    float* out = (float*)d_out;

    float* ws = (float*)d_ws;
    const size_t NF = (size_t)N_NODES * DIM;  // 6.4M floats
    float* h = ws;                            // fp32 [N,128]
    float* agg = ws + NF;                     // fp32 [N,128] (agg -> h1 -> h2 in place)
    short* whi = (short*)(ws + 2 * NF);       // bf16 hi [6][128][128]
    short* wlo = whi + 6 * DIM * DIM;         // bf16 lo [6][128][128]
    float* stats3 = ws + 2 * NF + 49152;      // 3*256 floats (wt total = 49152 floats)
    int* deg = (int*)(stats3 + 3 * 256);      // adjacent to stats3 for one memset
    int* ptr = deg + N_NODES;
    int* cursor = ptr + N_NODES + 1;
    int* esrc = cursor + N_NODES;
    int* partials = esrc + N_EDGES;  // 64 ints

    hipMemsetAsync(out, 0, (size_t)N_GRAPHS * OUT_STRIDE * sizeof(float), stream);
    hipMemsetAsync(stats3, 0, (3 * 256) * sizeof(float) + N_NODES * sizeof(int), stream);

    // CSR build (once; reused by all layers)
    degree_kernel<<<(N_EDGES + 255) / 256, 256, 0, stream>>>(dstp, deg);
    scan1_kernel<<<N_CHUNKS, 1024, 0, stream>>>(deg, ptr, partials);
    scan2_kernel<<<1, 64, 0, stream>>>(partials);
    scan3_kernel<<<(N_NODES + 256) / 256, 256, 0, stream>>>(partials, ptr, cursor);
    fill_kernel<<<(N_EDGES + 255) / 256, 256, 0, stream>>>(srcp, dstp, cursor, esrc);
    wconv_kernel<<<(6 * DIM * DIM + 255) / 256, 256, 0, stream>>>(W1s, W2s, whi, wlo);

    const int gemm_grid = (N_NODES + 127) / 128;  // 391
    const float* hin = x;
    for (int layer = 0; layer < N_LAYERS; ++layer) {
        gather_kernel<<<(N_NODES * 64 + 255) / 256, 256, 0, stream>>>(hin, ptr, esrc, agg);
        // h1 = relu(agg @ W1 + b1), in place
        mfma_gemm_kernel<<<gemm_grid, 256, 0, stream>>>(
            agg, whi + ((size_t)layer << 14), wlo + ((size_t)layer << 14), b1s + layer * DIM, agg);
        // h2 = relu(h1 @ W2 + b2), in place
        mfma_gemm_kernel<<<gemm_grid, 256, 0, stream>>>(
            agg, whi + ((size_t)(3 + layer) << 14), wlo + ((size_t)(3 + layer) << 14),
            b2s + layer * DIM, agg);
        float* stats = stats3 + layer * 256;
        bn_stats_kernel<<<512, 256, 0, stream>>>(agg, stats);
        bn_apply_pool_kernel<<<gemm_grid, 128, 0, stream>>>(agg, stats, gammas + layer * DIM,
                                                            betas + layer * DIM, batch, h, out,
                                                            layer);
        hin = h;
    }
}

// Round 5
// 572.201 us; speedup vs baseline: 6.3493x; 1.1251x over previous
//
#include <hip/hip_runtime.h>

#define N_NODES 50000
#define N_EDGES 600000
#define DIM 128
#define N_GRAPHS 512
#define N_LAYERS 3
#define OUT_STRIDE (N_LAYERS * DIM)
#define BN_EPS 1e-5f
#define N_CHUNKS 49  // ceil(50000/1024)

typedef __attribute__((ext_vector_type(8))) short short8;
typedef __attribute__((ext_vector_type(4))) float floatx4;

__device__ inline short f2bf(float f) {
    union { float f; unsigned u; } x{f};
    unsigned r = x.u + 0x7fffu + ((x.u >> 16) & 1u);
    return (short)(r >> 16);
}
__device__ inline float bf2f(short h) {
    union { unsigned u; float f; } x;
    x.u = ((unsigned)(unsigned short)h) << 16;
    return x.f;
}
// exact truncation split: f == bf2f(hi) + bf2f(lo) + O(2^-16 |f|)
__device__ inline void split_trunc(float f, short& hi, short& lo) {
    union { float f; unsigned u; } x{f};
    hi = (short)(x.u >> 16);
    union { unsigned u; float f; } hf;
    hf.u = x.u & 0xffff0000u;
    union { float f; unsigned u; } y{f - hf.f};
    lo = (short)(y.u >> 16);
}

// ---------------- CSR build ----------------
__global__ __launch_bounds__(256) void degree_kernel(const int* __restrict__ dst,
                                                     int* __restrict__ deg) {
    int e = blockIdx.x * 256 + threadIdx.x;
    if (e < N_EDGES) atomicAdd(&deg[dst[e]], 1);
}

__global__ __launch_bounds__(1024) void scan1_kernel(const int* __restrict__ deg,
                                                     int* __restrict__ ptr,
                                                     int* __restrict__ partials) {
    __shared__ int buf[1024];
    int i = blockIdx.x * 1024 + threadIdx.x;
    int v = (i < N_NODES) ? deg[i] : 0;
    buf[threadIdx.x] = v;
    __syncthreads();
    for (int off = 1; off < 1024; off <<= 1) {
        int t = (threadIdx.x >= (unsigned)off) ? buf[threadIdx.x - off] : 0;
        __syncthreads();
        buf[threadIdx.x] += t;
        __syncthreads();
    }
    if (i < N_NODES) ptr[i] = buf[threadIdx.x] - v;  // chunk-local exclusive
    if (threadIdx.x == 1023) partials[blockIdx.x] = buf[1023];
}

__global__ __launch_bounds__(64) void scan2_kernel(int* __restrict__ partials) {
    if (threadIdx.x == 0) {
        int run = 0;
        for (int i = 0; i < N_CHUNKS; ++i) { int t = partials[i]; partials[i] = run; run += t; }
    }
}

__global__ __launch_bounds__(256) void scan3_kernel(const int* __restrict__ partials,
                                                    int* __restrict__ ptr,
                                                    int* __restrict__ cursor) {
    int i = blockIdx.x * 256 + threadIdx.x;
    if (i < N_NODES) {
        int p = ptr[i] + partials[i >> 10];
        ptr[i] = p;
        cursor[i] = p;
    }
    if (i == N_NODES) ptr[N_NODES] = N_EDGES;
}

__global__ __launch_bounds__(256) void fill_kernel(const int* __restrict__ src,
                                                   const int* __restrict__ dst,
                                                   int* __restrict__ cursor,
                                                   int* __restrict__ esrc) {
    int e = blockIdx.x * 256 + threadIdx.x;
    if (e < N_EDGES) {
        int slot = atomicAdd(&cursor[dst[e]], 1);
        esrc[slot] = src[e];
    }
}

__global__ __launch_bounds__(256) void count_kernel(const int* __restrict__ batch,
                                                    int* __restrict__ cnt) {
    int i = blockIdx.x * 256 + threadIdx.x;
    if (i < N_NODES) atomicAdd(&cnt[batch[i]], 1);
}

// ---------------- weight convert: W[k][n] -> Wt_hi/lo[mat][n][k] (split bf16) ----------------
__global__ __launch_bounds__(256) void wconv_kernel(const float* __restrict__ W1s,
                                                    const float* __restrict__ W2s,
                                                    short* __restrict__ Whi,
                                                    short* __restrict__ Wlo) {
    int idx = blockIdx.x * 256 + threadIdx.x;
    if (idx >= 6 * DIM * DIM) return;
    int mat = idx >> 14;
    int e = idx & 16383;
    int k = e >> 7, n = e & 127;
    const float* W = (mat < 3) ? (W1s + (size_t)mat * DIM * DIM)
                               : (W2s + (size_t)(mat - 3) * DIM * DIM);
    float w = W[e];
    short hi = f2bf(w);
    short lo = f2bf(w - bf2f(hi));
    size_t o = ((size_t)mat << 14) + n * DIM + k;
    Whi[o] = hi;
    Wlo[o] = lo;
}

// ---- gather + inline prev-layer BN affine: agg[n] = G*(h2[n]+sum h2[j]) + (deg+1)*OFF ----
__global__ __launch_bounds__(256) void gather_kernel(const float* __restrict__ hin,
                                                     const int* __restrict__ ptr,
                                                     const int* __restrict__ esrc,
                                                     const float* __restrict__ stats,  // null=>id
                                                     const float* __restrict__ gamma,
                                                     const float* __restrict__ beta,
                                                     float* __restrict__ agg) {
    int node = (blockIdx.x * 256 + threadIdx.x) >> 6;
    int lane = threadIdx.x & 63;
    if (node >= N_NODES) return;
    float Gx = 1.f, Gy = 1.f, Ox = 0.f, Oy = 0.f;
    if (stats) {
        int c0 = lane * 2;
        const float invn = 1.0f / (float)N_NODES;
        float m0 = stats[c0] * invn, m1 = stats[c0 + 1] * invn;
        float v0 = stats[128 + c0] * invn - m0 * m0;
        float v1 = stats[128 + c0 + 1] * invn - m1 * m1;
        float i0 = rsqrtf(v0 + BN_EPS), i1 = rsqrtf(v1 + BN_EPS);
        Gx = gamma[c0] * i0;
        Gy = gamma[c0 + 1] * i1;
        Ox = beta[c0] - m0 * Gx;
        Oy = beta[c0 + 1] - m1 * Gy;
    }
    const float2* h2p = (const float2*)hin;
    float2 acc = h2p[(size_t)node * 64 + lane];  // self term (eps=0)
    int b = ptr[node], e = ptr[node + 1];
    int j = b;
    // unroll by 4: 4 independent row loads in flight (latency-bound loop)
    for (; j + 4 <= e; j += 4) {
        int s0 = esrc[j], s1 = esrc[j + 1], s2 = esrc[j + 2], s3 = esrc[j + 3];
        float2 v0 = h2p[(size_t)s0 * 64 + lane];
        float2 v1 = h2p[(size_t)s1 * 64 + lane];
        float2 v2 = h2p[(size_t)s2 * 64 + lane];
        float2 v3 = h2p[(size_t)s3 * 64 + lane];
        acc.x += (v0.x + v1.x) + (v2.x + v3.x);
        acc.y += (v0.y + v1.y) + (v2.y + v3.y);
    }
    for (; j < e; ++j) {
        int s = esrc[j];
        float2 v = h2p[(size_t)s * 64 + lane];
        acc.x += v.x;
        acc.y += v.y;
    }
    float dp1 = (float)(e - b + 1);
    float2 r;
    r.x = fmaf(Gx, acc.x, dp1 * Ox);
    r.y = fmaf(Gy, acc.y, dp1 * Oy);
    ((float2*)agg)[(size_t)node * 64 + lane] = r;
}

// ---------------- fused MLP: out = relu(relu(in@W1+b1)@W2+b2), split-bf16 MFMA ----------------
// 128-row block, 4 waves; wave = 32 rows x 128 cols (2x8 MFMA tiles of 16x16x32).
// A hi/lo staged in LDS (XOR swizzle); h1 round-trips through same LDS as packed (hi|lo) u32.
// W hi/lo fragments streamed from global (L2-resident).
__global__ __launch_bounds__(256) void mlp_kernel(const float* __restrict__ in,
                                                  const short* __restrict__ W1hi,
                                                  const short* __restrict__ W1lo,
                                                  const float* __restrict__ b1,
                                                  const short* __restrict__ W2hi,
                                                  const short* __restrict__ W2lo,
                                                  const float* __restrict__ b2,
                                                  float* __restrict__ out) {
    __shared__ unsigned sbuf[16384];  // 64 KB, aliased across phases
    short* As_hi = (short*)sbuf;             // [128][128] shorts, chunk^row swizzle
    short* As_lo = (short*)(sbuf + 8192);
    const int tid = threadIdx.x;
    const int base = blockIdx.x * 128;

    // phase 0: stage A (fp32 -> hi/lo trunc split)
    const float4* asrc = (const float4*)in;
#pragma unroll
    for (int it = 0; it < 8; ++it) {
        int c = tid + it * 256;  // 0..2047
        int r = c >> 4, ch = c & 15;
        int row = base + r;
        float4 v0 = make_float4(0.f, 0.f, 0.f, 0.f), v1 = v0;
        if (row < N_NODES) {
            v0 = asrc[(size_t)row * 32 + ch * 2];
            v1 = asrc[(size_t)row * 32 + ch * 2 + 1];
        }
        float f[8] = {v0.x, v0.y, v0.z, v0.w, v1.x, v1.y, v1.z, v1.w};
        short8 hi, lo;
#pragma unroll
        for (int j = 0; j < 8; ++j) {
            short h, l;
            split_trunc(f[j], h, l);
            hi[j] = h;
            lo[j] = l;
        }
        int pos = r * 128 + ((ch ^ (r & 15)) * 8);
        *(short8*)&As_hi[pos] = hi;
        *(short8*)&As_lo[pos] = lo;
    }
    __syncthreads();

    const int wave = tid >> 6;
    const int lane = tid & 63;
    const int wm = wave * 32;
    const int l15 = lane & 15;
    const int quad = lane >> 4;

    // phase 1: preload all A fragments, then GEMM1 (no LDS access during MFMA)
    short8 Ahi[4][2], Alo[4][2];
#pragma unroll
    for (int ks = 0; ks < 4; ++ks)
#pragma unroll
        for (int mi = 0; mi < 2; ++mi) {
            int row = wm + mi * 16 + l15;
            int pos = row * 128 + (((ks * 4 + quad) ^ l15) * 8);
            Ahi[ks][mi] = *(const short8*)&As_hi[pos];
            Alo[ks][mi] = *(const short8*)&As_lo[pos];
        }
    floatx4 acc[2][8];
#pragma unroll
    for (int mi = 0; mi < 2; ++mi)
#pragma unroll
        for (int ni = 0; ni < 8; ++ni) acc[mi][ni] = floatx4{0.f, 0.f, 0.f, 0.f};
#pragma unroll
    for (int ks = 0; ks < 4; ++ks) {
#pragma unroll
        for (int ni = 0; ni < 8; ++ni) {
            size_t p = (size_t)(ni * 16 + l15) * DIM + ks * 32 + quad * 8;
            short8 bhi = *(const short8*)&W1hi[p];
            short8 blo = *(const short8*)&W1lo[p];
#pragma unroll
            for (int mi = 0; mi < 2; ++mi) {
                acc[mi][ni] = __builtin_amdgcn_mfma_f32_16x16x32_bf16(Ahi[ks][mi], bhi, acc[mi][ni], 0, 0, 0);
                acc[mi][ni] = __builtin_amdgcn_mfma_f32_16x16x32_bf16(Alo[ks][mi], bhi, acc[mi][ni], 0, 0, 0);
                acc[mi][ni] = __builtin_amdgcn_mfma_f32_16x16x32_bf16(Ahi[ks][mi], blo, acc[mi][ni], 0, 0, 0);
            }
        }
    }
    __syncthreads();  // all As reads complete before overwrite

    // phase 2: bias1 + relu, trunc-split, pack (hi<<16|lo) -> LDS u32 [row][col], 16B-chunk swizzle
#pragma unroll
    for (int mi = 0; mi < 2; ++mi)
#pragma unroll
        for (int ni = 0; ni < 8; ++ni) {
            float bv = b1[ni * 16 + l15];
            int col = ni * 16 + l15;
#pragma unroll
            for (int reg = 0; reg < 4; ++reg) {
                int row = wm + mi * 16 + quad * 4 + reg;
                float v = fmaxf(acc[mi][ni][reg] + bv, 0.f);
                union { float f; unsigned u; } x{v};
                union { unsigned u; float f; } hf;
                hf.u = x.u & 0xffff0000u;
                union { float f; unsigned u; } y{v - hf.f};
                unsigned w = hf.u | (y.u >> 16);
                sbuf[row * 128 + ((((col >> 2) ^ (row & 31)) * 4) + (col & 3))] = w;
            }
        }
    __syncthreads();

    // phase 3: GEMM2 from packed h1
    floatx4 acc2[2][8];
#pragma unroll
    for (int mi = 0; mi < 2; ++mi)
#pragma unroll
        for (int ni = 0; ni < 8; ++ni) acc2[mi][ni] = floatx4{0.f, 0.f, 0.f, 0.f};
#pragma unroll
    for (int ks = 0; ks < 4; ++ks) {
        short8 ahi2[2], alo2[2];
#pragma unroll
        for (int mi = 0; mi < 2; ++mi) {
            int row = wm + mi * 16 + l15;
            int c5 = ks * 8 + quad * 2;
            unsigned w[8];
            *(uint4*)&w[0] = *(const uint4*)&sbuf[row * 128 + ((c5 ^ (row & 31)) * 4)];
            *(uint4*)&w[4] = *(const uint4*)&sbuf[row * 128 + (((c5 + 1) ^ (row & 31)) * 4)];
#pragma unroll
            for (int j = 0; j < 8; ++j) {
                ahi2[mi][j] = (short)(w[j] >> 16);
                alo2[mi][j] = (short)(w[j] & 0xffffu);
            }
        }
#pragma unroll
        for (int ni = 0; ni < 8; ++ni) {
            size_t p = (size_t)(ni * 16 + l15) * DIM + ks * 32 + quad * 8;
            short8 bhi = *(const short8*)&W2hi[p];
            short8 blo = *(const short8*)&W2lo[p];
#pragma unroll
            for (int mi = 0; mi < 2; ++mi) {
                acc2[mi][ni] = __builtin_amdgcn_mfma_f32_16x16x32_bf16(ahi2[mi], bhi, acc2[mi][ni], 0, 0, 0);
                acc2[mi][ni] = __builtin_amdgcn_mfma_f32_16x16x32_bf16(alo2[mi], bhi, acc2[mi][ni], 0, 0, 0);
                acc2[mi][ni] = __builtin_amdgcn_mfma_f32_16x16x32_bf16(ahi2[mi], blo, acc2[mi][ni], 0, 0, 0);
            }
        }
    }
    // epilogue: bias2 + relu -> global fp32 (raw h2)
#pragma unroll
    for (int mi = 0; mi < 2; ++mi)
#pragma unroll
        for (int ni = 0; ni < 8; ++ni) {
            float bv = b2[ni * 16 + l15];
            int col = ni * 16 + l15;
#pragma unroll
            for (int reg = 0; reg < 4; ++reg) {
                int row = base + wm + mi * 16 + quad * 4 + reg;
                if (row < N_NODES) out[(size_t)row * DIM + col] = fmaxf(acc2[mi][ni][reg] + bv, 0.f);
            }
        }
}

// ------- fused BN stats + raw segmented pool (batch sorted): one pass over h2 -------
__global__ __launch_bounds__(256) void stats_pool_kernel(const float* __restrict__ h2,
                                                         const int* __restrict__ batch,
                                                         float* __restrict__ stats,
                                                         float* __restrict__ out, int layer) {
    int c = threadIdx.x & 127;
    int rs = threadIdx.x >> 7;
    int r0 = blockIdx.x * 128 + rs * 64;
    int r1 = min(r0 + 64, N_NODES);
    if (r0 >= r1) return;
    float sum = 0.f, sq = 0.f, pacc = 0.f;
    int curb = batch[r0];
    for (int r = r0; r < r1; ++r) {
        int bb = batch[r];
        if (bb != curb) {
            atomicAdd(&out[(size_t)curb * OUT_STRIDE + layer * DIM + c], pacc);
            pacc = 0.f;
            curb = bb;
        }
        float v = h2[(size_t)r * DIM + c];
        sum += v;
        sq += v * v;
        pacc += v;
    }
    atomicAdd(&out[(size_t)curb * OUT_STRIDE + layer * DIM + c], pacc);
    atomicAdd(&stats[c], sum);
    atomicAdd(&stats[128 + c], sq);
}

// ------- finalize: out[b, l*128+c] = G_l[c]*rawpool + cnt[b]*OFF_l[c] -------
__global__ __launch_bounds__(384) void finalize_kernel(const float* __restrict__ stats3,
                                                       const float* __restrict__ gammas,
                                                       const float* __restrict__ betas,
                                                       const int* __restrict__ cnt,
                                                       float* __restrict__ out) {
    int b = blockIdx.x;
    int l = threadIdx.x >> 7, c = threadIdx.x & 127;
    const float invn = 1.0f / (float)N_NODES;
    const float* st = stats3 + l * 256;
    float m = st[c] * invn;
    float var = st[128 + c] * invn - m * m;
    float inv = rsqrtf(var + BN_EPS);
    float G = gammas[l * DIM + c] * inv;
    float OFF = betas[l * DIM + c] - m * G;
    size_t o = (size_t)b * OUT_STRIDE + threadIdx.x;
    out[o] = fmaf(G, out[o], (float)cnt[b] * OFF);
}

extern "C" void kernel_launch(void* const* d_in, const int* in_sizes, int n_in,
                              void* d_out, int out_size, void* d_ws, size_t ws_size,
                              hipStream_t stream) {
    const float* x = (const float*)d_in[0];
    const int* ei = (const int*)d_in[1];
    const int* srcp = ei;
    const int* dstp = ei + N_EDGES;
    const int* batch = (const int*)d_in[2];
    const float* W1s = (const float*)d_in[3];
    const float* b1s = (const float*)d_in[4];
    const float* W2s = (const float*)d_in[5];
    const float* b2s = (const float*)d_in[6];
    const float* gammas = (const float*)d_in[7];
    const float* betas = (const float*)d_in[8];
    float* out = (float*)d_out;

    float* ws = (float*)d_ws;
    const size_t NF = (size_t)N_NODES * DIM;  // 6.4M floats
    float* hbuf = ws;                         // fp32 [N,128] raw h2 of current layer
    float* agg = ws + NF;                     // fp32 [N,128]
    short* whi = (short*)(ws + 2 * NF);       // bf16 hi [6][128][128] (98304 shorts)
    short* wlo = whi + 6 * DIM * DIM;         // bf16 lo [6][128][128]
    float* stats3 = ws + 2 * NF + 98304 / 2 * 2;  // = ws + 2NF + 98304 floats? no:
    // whi+wlo = 196608 shorts = 98304 floats
    stats3 = ws + 2 * NF + 98304;             // 3*256 floats
    int* cnt = (int*)(stats3 + 3 * 256);      // 512
    int* deg = cnt + N_GRAPHS;                // 50000
    int* ptr = deg + N_NODES;                 // 50001
    int* cursor = ptr + N_NODES + 1;          // 50000
    int* esrc = cursor + N_NODES;             // 600000
    int* partials = esrc + N_EDGES;           // 64

    hipMemsetAsync(out, 0, (size_t)N_GRAPHS * OUT_STRIDE * sizeof(float), stream);
    // zero stats3 + cnt + deg (contiguous)
    hipMemsetAsync(stats3, 0, (3 * 256) * sizeof(float) + (N_GRAPHS + N_NODES) * sizeof(int),
                   stream);

    // CSR build (once; reused by all layers) + per-graph node counts
    degree_kernel<<<(N_EDGES + 255) / 256, 256, 0, stream>>>(dstp, deg);
    scan1_kernel<<<N_CHUNKS, 1024, 0, stream>>>(deg, ptr, partials);
    scan2_kernel<<<1, 64, 0, stream>>>(partials);
    scan3_kernel<<<(N_NODES + 256) / 256, 256, 0, stream>>>(partials, ptr, cursor);
    fill_kernel<<<(N_EDGES + 255) / 256, 256, 0, stream>>>(srcp, dstp, cursor, esrc);
    count_kernel<<<(N_NODES + 255) / 256, 256, 0, stream>>>(batch, cnt);
    wconv_kernel<<<(6 * DIM * DIM + 255) / 256, 256, 0, stream>>>(W1s, W2s, whi, wlo);

    const int nblk = (N_NODES + 127) / 128;  // 391
    for (int layer = 0; layer < N_LAYERS; ++layer) {
        const float* hin = (layer == 0) ? x : hbuf;
        const float* stp = (layer == 0) ? nullptr : (stats3 + (layer - 1) * 256);
        const float* gp = gammas + (layer - 1) * DIM;  // unused when stp==null
        const float* bp = betas + (layer - 1) * DIM;
        gather_kernel<<<(N_NODES * 64 + 255) / 256, 256, 0, stream>>>(hin, ptr, esrc, stp, gp, bp,
                                                                      agg);
        mlp_kernel<<<nblk, 256, 0, stream>>>(
            agg, whi + ((size_t)layer << 14), wlo + ((size_t)layer << 14), b1s + layer * DIM,
            whi + ((size_t)(3 + layer) << 14), wlo + ((size_t)(3 + layer) << 14),
            b2s + layer * DIM, hbuf);
        stats_pool_kernel<<<nblk, 256, 0, stream>>>(hbuf, batch, stats3 + layer * 256, out, layer);
    }
    finalize_kernel<<<N_GRAPHS, 384, 0, stream>>>(stats3, gammas, betas, cnt, out);
}